// Round 13
// baseline (45.501 us; speedup 1.0000x reference)
//
#include <hip/hip_runtime.h>
#include <stdint.h>

// Spatial transformer: batched dense-displacement trilinear warp.
// z-marching ring-buffer LDS pipeline, RING=16 (mask slots), step=4, tile 16x16.
// vol: [B=2, D=128, H=192, W=192, 1] f32
// trf: [B=2, D=128, H=192, W=192, 3] f32 (displacement along z,y,x)
// out: [B=2, D=128, H=192, W=192, 1] f32

#define BD 128
#define BH 192
#define BW 192
#define DHW (BD*BH*BW)
#define NB 2

// xy tile 16x16, block marches 4 z-steps of 4 -> 16 z, 4096 voxels/block
#define TX 16
#define TY 16
#define NTX (BW/TX)                 // 12
#define NTY (BH/TY)                 // 12
#define ZSTEP 4
#define NSTEPB 4
#define BLKZ (ZSTEP*NSTEPB)         // 16
#define NZB (BD/BLKZ)               // 8
#define NBLK (NTX*NTY*NZB*NB)       // 2304 (%8==0)
#define NXCD 8

// staged slab: x 32 [tx-8..tx+23] * y 24 [ty-4..ty+19], one z = 768 floats = 3KB
// ring of 16 slabs (slot = z & 15) = 48KB -> 3 blocks/CU.
// alive at step k (ZS=zA+4k): window [ZS-4, ZS+7] (12) + prefetch [ZS+8, ZS+11] (4)
// = 16 distinct mod 16; prefetch slots == slots of z [ZS-8, ZS-5], dead since the
// window advanced past them at step k-1's barrier.
#define SXW 32
#define SYW 24
#define SLAB (SXW*SYW)              // 768 floats
#define CHSLAB (SLAB/4)             // 192 chunks of 16B
#define RING 16
#define LDSF (RING*SLAB)            // 12288 floats = 49152 B

typedef float f4v __attribute__((ext_vector_type(4)));

__global__ __launch_bounds__(256, 3) void st_warp_kernel(
    const float* __restrict__ vol,
    const float* __restrict__ trf,
    float* __restrict__ out)
{
    __shared__ __align__(16) float lds[LDSF];

    // XCD-chunked swizzle (2304 % 8 == 0 -> bijective)
    const int bid = blockIdx.x;
    const int swz = (bid % NXCD) * (NBLK / NXCD) + bid / NXCD;
    int t = swz;
    const int txi = t % NTX; t /= NTX;
    const int tyi = t % NTY; t /= NTY;
    const int kzb = t % NZB; t /= NZB;
    const int b   = t;
    const int tx = txi*TX, ty = tyi*TY;
    const int zA = kzb * BLKZ;                  // first output z of this block

    const int sx = min(max(tx - 8, 0), BW - SXW);   // multiple of 8 -> 16B aligned
    const int sy = min(max(ty - 4, 0), BH - SYW);

    const int tid = (int)threadIdx.x;
    const float* volb = vol + (size_t)b * DHW;

    // thread's voxel-quad within a step: x = Xb..Xb+3, y = Y, z = ZS + zb
    const int xq = tid & 3;
    const int yb = (tid >> 2) & 15;
    const int zb = tid >> 6;                    // wave-uniform
    const int Y  = ty + yb;
    const int Xb = tx + xq*4;
    const f4v* trf4 = (const f4v*)trf;

    // ---- stage nslab slabs [zfirst, zfirst+nslab) into ring slots (z & 15) ----
    // chunk f: slab f/192, within-slab s (yi=s>>3, c=s&7). nch always %256==0.
    // 192 % 64 == 0 -> a wave's 64-chunk run never straddles a slab -> slot
    // uniform per wave -> LDS dest stays base + lane*16 (linear, required).
    auto stage = [&](int zfirst, int nslab) {
        const int iters = (nslab * CHSLAB) >> 8;
        for (int it = 0; it < iters; ++it) {
            const int f  = tid + it*256;
            const int sl = (int)((unsigned)f / (unsigned)CHSLAB);  // magic-div
            const int s  = f - sl*CHSLAB;
            const int z  = zfirst + sl;
            const int yi = s >> 3;
            const int c  = s & 7;
            const int slot = z & (RING-1);
            const float* g = volb + ((size_t)(z*BH + sy + yi))*BW + sx + (c<<2);
            __builtin_amdgcn_global_load_lds(
                (const __attribute__((address_space(1))) void*)g,
                (__attribute__((address_space(3))) void*)&lds[slot*SLAB + (s<<2)],
                16, 0, 0);
        }
    };

    auto load_trf = [&](int ZSL, f4v& TA, f4v& TB, f4v& TC) {
        const size_t rowb = ((size_t)((b*BD + ZSL + zb)*BH + Y))*BW;
        const size_t rowf4 = (rowb + tx) * 3 / 4;
        TA = trf4[rowf4 + 3*xq + 0];
        TB = trf4[rowf4 + 3*xq + 1];
        TC = trf4[rowf4 + 3*xq + 2];
    };

    // ---- compute one step: 4 voxels at z = ZS + zb, from ring-resident slabs ----
    auto compute_vals = [&](int ZS, f4v tA, f4v tB, f4v tC) -> f4v {
        const int Z   = ZS + zb;
        const int wlo = max(0, ZS - 4);
        const int whi = min(BD - 1, ZS + 7);
        const float dzs[4] = {tA.x, tA.w, tB.z, tC.y};
        const float dys[4] = {tA.y, tB.x, tB.w, tC.z};
        const float dxs[4] = {tA.z, tB.y, tC.x, tC.w};
        float res[4];
#pragma unroll
        for (int jj = 0; jj < 4; ++jj) {
            // high-clamp only; low-side misses fail inwin -> fallback clamps ints
            float cz = fminf((float)Z + dzs[jj], (float)(BD-1));
            float cy = fminf((float)Y + dys[jj], (float)(BH-1));
            float cx = fminf((float)(Xb+jj) + dxs[jj], (float)(BW-1));
            float fz = floorf(cz), fy = floorf(cy), fx = floorf(cx);
            int z0 = (int)fz, y0 = (int)fy, x0 = (int)fx;
            int z1 = min(z0+1, BD-1);
            int y1 = min(y0+1, BH-1);
            int x1 = min(x0+1, BW-1);
            float wz = cz - fz, wy = cy - fy, wx = cx - fx;
            float v000,v001,v010,v011,v100,v101,v110,v111;
            bool inwin = (x0 >= sx) & (x1 <= sx+SXW-1) & (y0 >= sy) & (y1 <= sy+SYW-1)
                       & (z0 >= wlo) & (z1 <= whi);
            if (inwin) {
                const int xi  = x0 - sx;              // [0,31] (cx high-clamped)
                const int xiA = min(xi, SXW-2);       // x==191 edge: pair + select
                const bool lo = xi < SXW-1;
                const int sl0 = z0 & (RING-1);
                const int sl1 = z1 & (RING-1);        // z1==z0 at top edge -> same slot
                const int yi0 = y0 - sy, yi1 = y1 - sy;
                const int rA = sl0*SLAB + (yi0<<5) + xiA;
                const int rB = sl0*SLAB + (yi1<<5) + xiA;
                const int rC = sl1*SLAB + (yi0<<5) + xiA;
                const int rD = sl1*SLAB + (yi1<<5) + xiA;
                float a00 = lds[rA], b00 = lds[rA+1];
                float a01 = lds[rB], b01 = lds[rB+1];
                float a10 = lds[rC], b10 = lds[rC+1];
                float a11 = lds[rD], b11 = lds[rD+1];
                v000 = lo ? a00 : b00;  v001 = b00;
                v010 = lo ? a01 : b01;  v011 = b01;
                v100 = lo ? a10 : b10;  v101 = b10;
                v110 = lo ? a11 : b11;  v111 = b11;
            } else {
                // exact path with full clamping of integer corners (low side);
                // when corners collide the weight cancels -> matches reference.
                const int z0c = max(z0, 0), z1c = max(z1, 0);
                const int y0c = max(y0, 0), y1c = max(y1, 0);
                const int x0c = max(x0, 0), x1c = max(x1, 0);
                const float* p00 = volb + ((size_t)z0c*BH + y0c)*BW;
                const float* p01 = volb + ((size_t)z0c*BH + y1c)*BW;
                const float* p10 = volb + ((size_t)z1c*BH + y0c)*BW;
                const float* p11 = volb + ((size_t)z1c*BH + y1c)*BW;
                v000 = p00[x0c]; v001 = p00[x1c];
                v010 = p01[x0c]; v011 = p01[x1c];
                v100 = p10[x0c]; v101 = p10[x1c];
                v110 = p11[x0c]; v111 = p11[x1c];
            }
            float c00 = v000 + wx*(v001-v000);
            float c01 = v010 + wx*(v011-v010);
            float c10 = v100 + wx*(v101-v100);
            float c11 = v110 + wx*(v111-v110);
            float c0  = c00 + wy*(c01-c00);
            float c1  = c10 + wy*(c11-c10);
            res[jj]   = c0 + wz*(c1-c0);
        }
        f4v r = {res[0], res[1], res[2], res[3]};
        return r;
    };

    // ---------------- pipeline ----------------
    f4v TA[2], TB[2], TC[2];
    // prologue: first window [max(0,zA-4), zA+7] + trf for step 0
    stage(max(0, zA - 4), (zA == 0) ? 8 : 12);
    load_trf(zA, TA[0], TB[0], TC[0]);
    __syncthreads();

#pragma unroll
    for (int k = 0; k < NSTEPB; ++k) {
        const int ZS = zA + k*ZSTEP;
        if (k + 1 < NSTEPB) {
            const int zn = ZS + 8;                 // new slabs for next window
            if (zn < BD) stage(zn, min(4, BD - zn));
            load_trf(ZS + ZSTEP, TA[(k+1)&1], TB[(k+1)&1], TC[(k+1)&1]);
        }
        f4v r = compute_vals(ZS, TA[k&1], TB[k&1], TC[k&1]);
        __syncthreads();
        // deferred store: after the barrier, so the barrier's vmcnt(0) drain
        // does not wait on these 4 HBM stores; they retire under the next step.
        const size_t of4 = (((size_t)((b*BD + ZS + zb)*BH + Y))*BW + Xb) / 4;
        __builtin_nontemporal_store(r, &((f4v*)out)[of4]);
    }
}

extern "C" void kernel_launch(void* const* d_in, const int* in_sizes, int n_in,
                              void* d_out, int out_size, void* d_ws, size_t ws_size,
                              hipStream_t stream) {
    const float* vol = (const float*)d_in[0];
    const float* trf = (const float*)d_in[1];
    float* out = (float*)d_out;

    st_warp_kernel<<<dim3(NBLK), dim3(256), 0, stream>>>(vol, trf, out);
}